// Round 1
// baseline (2422.783 us; speedup 1.0000x reference)
//
#include <hip/hip_runtime.h>
#include <hip/hip_bf16.h>

#define C       228
#define TT      1024
#define NPOS    2048      // B*T
#define LANESN  4
#define HD      57
#define VOC     50257
#define KPAD    256
#define HID     912
#define NLAYER  4

typedef __bf16 bf16x8 __attribute__((ext_vector_type(8)));
typedef float  f32x4  __attribute__((ext_vector_type(4)));

// ---------------- weight transpose (generic) ----------------
// src [R][Cc] row-major  ->  dst[c*dstStride + dstColOff + r] = src[r*Cc + c]
__global__ void transpose_k(const float* __restrict__ src, float* __restrict__ dst,
                            int R, int Cc, int dstStride, int dstColOff,
                            int srcLayerStride, int dstLayerStride) {
    int layer = blockIdx.y;
    src += (size_t)layer * srcLayerStride;
    dst += (size_t)layer * dstLayerStride;
    int i = blockIdx.x * 256 + threadIdx.x;
    if (i < R * Cc) {
        int r = i / Cc, c = i - r * Cc;
        dst[(size_t)c * dstStride + dstColOff + r] = src[i];
    }
}

// ---------------- embedding ----------------
__global__ void embed_k(const int* __restrict__ idx, const float* __restrict__ wte,
                        float* __restrict__ x) {
    int i = blockIdx.x * 256 + threadIdx.x;   // NPOS*C total
    int n = i / C, c = i - n * C;
    x[i] = wte[(size_t)idx[n] * C + c];
}

// ---------------- LN + dual matmul (qin = h@w_up^T, v = h@w_v^T) ----------------
// wuvT layout: [C][2C], cols 0..C-1 -> up, C..2C-1 -> v
__global__ __launch_bounds__(256) void lnuv_k(const float* __restrict__ x, const float* __restrict__ g,
                                              const float* __restrict__ wuvT,
                                              float* __restrict__ qout, float* __restrict__ vout) {
    __shared__ __align__(16) float hsh[8][232];
    int tid = threadIdx.x;
    int nb  = blockIdx.x * 8;
    int p   = tid >> 5, l32 = tid & 31;
    const float* xr = x + (size_t)(nb + p) * C;
    float vals[8];
    float s = 0.f, ss = 0.f;
#pragma unroll
    for (int j = 0; j < 8; ++j) {
        int c = l32 + j * 32;
        float vv = (c < C) ? xr[c] : 0.f;
        vals[j] = vv; s += vv; ss += vv * vv;
    }
#pragma unroll
    for (int o = 16; o > 0; o >>= 1) { s += __shfl_xor(s, o, 32); ss += __shfl_xor(ss, o, 32); }
    float mean = s * (1.f / C);
    float var  = ss * (1.f / C) - mean * mean;
    float rstd = rsqrtf(var + 1e-5f);
#pragma unroll
    for (int j = 0; j < 8; ++j) {
        int c = l32 + j * 32;
        if (c < C) hsh[p][c] = (vals[j] - mean) * rstd * g[c];
    }
    __syncthreads();
    for (int col = tid; col < 2 * C; col += 256) {
        float acc[8] = {0,0,0,0,0,0,0,0};
        const float* wcol = wuvT + col;
        for (int c4 = 0; c4 < C / 4; ++c4) {
            float w0 = wcol[(size_t)(c4*4+0)*(2*C)];
            float w1 = wcol[(size_t)(c4*4+1)*(2*C)];
            float w2 = wcol[(size_t)(c4*4+2)*(2*C)];
            float w3 = wcol[(size_t)(c4*4+3)*(2*C)];
#pragma unroll
            for (int pp = 0; pp < 8; ++pp) {
                float4 h4 = *(const float4*)&hsh[pp][c4*4];
                acc[pp] = fmaf(h4.x, w0, acc[pp]);
                acc[pp] = fmaf(h4.y, w1, acc[pp]);
                acc[pp] = fmaf(h4.z, w2, acc[pp]);
                acc[pp] = fmaf(h4.w, w3, acc[pp]);
            }
        }
        if (col < C) {
#pragma unroll
            for (int pp = 0; pp < 8; ++pp) qout[(size_t)(nb+pp)*C + col] = acc[pp];
        } else {
#pragma unroll
            for (int pp = 0; pp < 8; ++pp) vout[(size_t)(nb+pp)*C + col - C] = acc[pp];
        }
    }
}

// ---------------- fused scan step ----------------
__global__ __launch_bounds__(256) void scan_k(const float* __restrict__ src, float* __restrict__ dst,
                                              const float* __restrict__ wscan,
                                              const float* __restrict__ ident, int off) {
    __shared__ __align__(16) float lsh[8][232];
    __shared__ __align__(16) float rsh[8][232];
    __shared__ __align__(16) float ush[8][232];
    __shared__ __align__(16) float vmsh[8][232];
    __shared__ __align__(16) float zsh[8][232];
    __shared__ float scsh[8][4][4];
    __shared__ float rssh[8][4];
    int tid = threadIdx.x;
    int nb  = blockIdx.x * 8;
    // load left/right/u
    for (int i = tid; i < 8 * C; i += 256) {
        int p = i / C, c = i - p * C;
        int n = nb + p;
        int t = n & (TT - 1);
        float r = src[(size_t)nb * C + i];
        float l = (t >= off) ? src[(size_t)nb * C + i - (size_t)off * C] : ident[c];
        lsh[p][c] = l; rsh[p][c] = r; ush[p][c] = l + r;
    }
    __syncthreads();
    // vmix = u @ wscan  (wscan [C][C] row-major, coalesced per-column)
    if (tid < C) {
        float acc[8] = {0,0,0,0,0,0,0,0};
        const float* wcol = wscan + tid;
        for (int c4 = 0; c4 < C / 4; ++c4) {
            float w0 = wcol[(size_t)(c4*4+0)*C];
            float w1 = wcol[(size_t)(c4*4+1)*C];
            float w2 = wcol[(size_t)(c4*4+2)*C];
            float w3 = wcol[(size_t)(c4*4+3)*C];
#pragma unroll
            for (int pp = 0; pp < 8; ++pp) {
                float4 u4 = *(const float4*)&ush[pp][c4*4];
                acc[pp] = fmaf(u4.x, w0, acc[pp]);
                acc[pp] = fmaf(u4.y, w1, acc[pp]);
                acc[pp] = fmaf(u4.z, w2, acc[pp]);
                acc[pp] = fmaf(u4.w, w3, acc[pp]);
            }
        }
#pragma unroll
        for (int pp = 0; pp < 8; ++pp) vmsh[pp][tid] = acc[pp];
    }
    __syncthreads();
    // scores[l][m] = q_l . k_m / sqrt(HD)
    if (tid < 128) {
        int p = tid >> 4, l = (tid >> 2) & 3, m = tid & 3;
        const float* qv = &lsh[p][l * HD];
        const float* kv = &rsh[p][m * HD];
        float sc = 0.f;
        for (int d = 0; d < HD; ++d) sc = fmaf(qv[d], kv[d], sc);
        scsh[p][l][m] = sc * 0.13245323570650439f;  // 1/sqrt(57)
    }
    __syncthreads();
    // softmax over m
    if (tid < 32) {
        int p = tid >> 2, l = tid & 3;
        float s0 = scsh[p][l][0], s1 = scsh[p][l][1], s2 = scsh[p][l][2], s3 = scsh[p][l][3];
        float mx = fmaxf(fmaxf(s0, s1), fmaxf(s2, s3));
        float e0 = expf(s0 - mx), e1 = expf(s1 - mx), e2 = expf(s2 - mx), e3 = expf(s3 - mx);
        float inv = 1.f / (e0 + e1 + e2 + e3);
        scsh[p][l][0] = e0 * inv; scsh[p][l][1] = e1 * inv;
        scsh[p][l][2] = e2 * inv; scsh[p][l][3] = e3 * inv;
    }
    __syncthreads();
    // z = att @ vmix
    for (int i = tid; i < 8 * C; i += 256) {
        int p = i / C, c = i - p * C;
        int l = c / HD, d = c - l * HD;
        float z = scsh[p][l][0] * vmsh[p][d]
                + scsh[p][l][1] * vmsh[p][HD + d]
                + scsh[p][l][2] * vmsh[p][2 * HD + d]
                + scsh[p][l][3] * vmsh[p][3 * HD + d];
        zsh[p][c] = z;
    }
    __syncthreads();
    // rms factor per (p,l): rsqrt(mean(z^2)+1e-6)/(1+l)
    if (tid < 32) {
        int p = tid >> 2, l = tid & 3;
        float ssum = 0.f;
        for (int d = 0; d < HD; ++d) { float z = zsh[p][l * HD + d]; ssum = fmaf(z, z, ssum); }
        rssh[p][l] = rsqrtf(ssum * (1.f / HD) + 1e-6f) / (float)(1 + l);
    }
    __syncthreads();
    // out = left + z * rs
    for (int i = tid; i < 8 * C; i += 256) {
        int p = i / C, c = i - p * C;
        int l = c / HD;
        dst[(size_t)nb * C + i] = lsh[p][c] + zsh[p][c] * rssh[p][l];
    }
}

// ---------------- cproj: x += (q*v) @ w_cproj^T ----------------
__global__ __launch_bounds__(256) void cproj_k(const float* __restrict__ q, const float* __restrict__ v,
                                               const float* __restrict__ wcT, float* __restrict__ x) {
    __shared__ __align__(16) float psh[8][232];
    int tid = threadIdx.x, nb = blockIdx.x * 8;
    for (int i = tid; i < 8 * C; i += 256) {
        int p = i / C, c = i - p * C;
        psh[p][c] = q[(size_t)nb * C + i] * v[(size_t)nb * C + i];
    }
    __syncthreads();
    if (tid < C) {
        float acc[8] = {0,0,0,0,0,0,0,0};
        const float* wcol = wcT + tid;
        for (int c4 = 0; c4 < C / 4; ++c4) {
            float w0 = wcol[(size_t)(c4*4+0)*C];
            float w1 = wcol[(size_t)(c4*4+1)*C];
            float w2 = wcol[(size_t)(c4*4+2)*C];
            float w3 = wcol[(size_t)(c4*4+3)*C];
#pragma unroll
            for (int pp = 0; pp < 8; ++pp) {
                float4 h4 = *(const float4*)&psh[pp][c4*4];
                acc[pp] = fmaf(h4.x, w0, acc[pp]);
                acc[pp] = fmaf(h4.y, w1, acc[pp]);
                acc[pp] = fmaf(h4.z, w2, acc[pp]);
                acc[pp] = fmaf(h4.w, w3, acc[pp]);
            }
        }
#pragma unroll
        for (int pp = 0; pp < 8; ++pp) {
            size_t o = (size_t)(nb + pp) * C + tid;
            x[o] += acc[pp];
        }
    }
}

// ---------------- LN2 + fc + gelu(tanh approx) ----------------
__global__ __launch_bounds__(256) void lnfc_k(const float* __restrict__ x, const float* __restrict__ g,
                                              const float* __restrict__ wfcT, float* __restrict__ hid) {
    __shared__ __align__(16) float hsh[8][232];
    int tid = threadIdx.x;
    int nb  = blockIdx.x * 8;
    int p   = tid >> 5, l32 = tid & 31;
    const float* xr = x + (size_t)(nb + p) * C;
    float vals[8];
    float s = 0.f, ss = 0.f;
#pragma unroll
    for (int j = 0; j < 8; ++j) {
        int c = l32 + j * 32;
        float vv = (c < C) ? xr[c] : 0.f;
        vals[j] = vv; s += vv; ss += vv * vv;
    }
#pragma unroll
    for (int o = 16; o > 0; o >>= 1) { s += __shfl_xor(s, o, 32); ss += __shfl_xor(ss, o, 32); }
    float mean = s * (1.f / C);
    float var  = ss * (1.f / C) - mean * mean;
    float rstd = rsqrtf(var + 1e-5f);
#pragma unroll
    for (int j = 0; j < 8; ++j) {
        int c = l32 + j * 32;
        if (c < C) hsh[p][c] = (vals[j] - mean) * rstd * g[c];
    }
    __syncthreads();
    for (int col = tid; col < HID; col += 256) {
        float acc[8] = {0,0,0,0,0,0,0,0};
        const float* wcol = wfcT + col;
        for (int c4 = 0; c4 < C / 4; ++c4) {
            float w0 = wcol[(size_t)(c4*4+0)*HID];
            float w1 = wcol[(size_t)(c4*4+1)*HID];
            float w2 = wcol[(size_t)(c4*4+2)*HID];
            float w3 = wcol[(size_t)(c4*4+3)*HID];
#pragma unroll
            for (int pp = 0; pp < 8; ++pp) {
                float4 h4 = *(const float4*)&hsh[pp][c4*4];
                acc[pp] = fmaf(h4.x, w0, acc[pp]);
                acc[pp] = fmaf(h4.y, w1, acc[pp]);
                acc[pp] = fmaf(h4.z, w2, acc[pp]);
                acc[pp] = fmaf(h4.w, w3, acc[pp]);
            }
        }
#pragma unroll
        for (int pp = 0; pp < 8; ++pp) {
            float u = acc[pp];
            float th = tanhf(0.7978845608028654f * (u + 0.044715f * u * u * u));
            hid[(size_t)(nb + pp) * HID + col] = 0.5f * u * (1.f + th);
        }
    }
}

// ---------------- proj + residual: x += hid @ w_proj^T ----------------
__global__ __launch_bounds__(256) void proj_k(const float* __restrict__ hid,
                                              const float* __restrict__ wpT, float* __restrict__ x) {
    __shared__ __align__(16) float hsh[8][916];
    int tid = threadIdx.x, nb = blockIdx.x * 8;
    for (int i = tid; i < 8 * HID; i += 256) {
        int p = i / HID, c = i - p * HID;
        hsh[p][c] = hid[(size_t)nb * HID + i];
    }
    __syncthreads();
    if (tid < C) {
        float acc[8] = {0,0,0,0,0,0,0,0};
        const float* wcol = wpT + tid;
        for (int c4 = 0; c4 < HID / 4; ++c4) {
            float w0 = wcol[(size_t)(c4*4+0)*C];
            float w1 = wcol[(size_t)(c4*4+1)*C];
            float w2 = wcol[(size_t)(c4*4+2)*C];
            float w3 = wcol[(size_t)(c4*4+3)*C];
#pragma unroll
            for (int pp = 0; pp < 8; ++pp) {
                float4 h4 = *(const float4*)&hsh[pp][c4*4];
                acc[pp] = fmaf(h4.x, w0, acc[pp]);
                acc[pp] = fmaf(h4.y, w1, acc[pp]);
                acc[pp] = fmaf(h4.z, w2, acc[pp]);
                acc[pp] = fmaf(h4.w, w3, acc[pp]);
            }
        }
#pragma unroll
        for (int pp = 0; pp < 8; ++pp) {
            size_t o = (size_t)(nb + pp) * C + tid;
            x[o] += acc[pp];
        }
    }
}

// ---------------- bf16 conversions (K padded to 256 with zeros) ----------------
__global__ void convx_k(const float* __restrict__ x, __hip_bfloat16* __restrict__ xbf) {
    int i = blockIdx.x * 256 + threadIdx.x;    // NPOS*KPAD total
    int n = i >> 8, c = i & 255;
    xbf[i] = __float2bfloat16((c < C) ? x[(size_t)n * C + c] : 0.f);
}
__global__ void convw_k(const float* __restrict__ wte, __hip_bfloat16* __restrict__ wbf) {
    size_t i = (size_t)blockIdx.x * 256 + threadIdx.x;   // VOC*KPAD total
    size_t n = i >> 8; int c = (int)(i & 255);
    wbf[i] = __float2bfloat16((c < C) ? wte[n * C + c] : 0.f);
}

// ---------------- lm_head: out[2048][VOC] = A[2048][256] @ B[VOC][256]^T (bf16 MFMA) ----------------
__global__ __launch_bounds__(256) void lmhead_k(const __bf16* __restrict__ A,
                                                const __bf16* __restrict__ Bw,
                                                float* __restrict__ out) {
    int lane = threadIdx.x & 63;
    int wave = threadIdx.x >> 6;
    int wm = wave >> 1, wn = wave & 1;
    int m0 = blockIdx.x * 128 + wm * 64;
    int n0 = blockIdx.y * 128 + wn * 64;
    int r  = lane & 15, q = lane >> 4;
    f32x4 acc[4][4] = {};
    const __bf16* Ap = A + (size_t)(m0 + r) * KPAD + q * 8;
    int brow[4];
#pragma unroll
    for (int nt = 0; nt < 4; ++nt) { int rw = n0 + nt * 16 + r; brow[nt] = (rw < VOC) ? rw : 0; }
    for (int kc = 0; kc < 8; ++kc) {
        int ko = kc * 32;
        bf16x8 a[4], b[4];
#pragma unroll
        for (int mt = 0; mt < 4; ++mt)
            a[mt] = *(const bf16x8*)(Ap + (size_t)mt * 16 * KPAD + ko);
#pragma unroll
        for (int nt = 0; nt < 4; ++nt)
            b[nt] = *(const bf16x8*)(Bw + (size_t)brow[nt] * KPAD + q * 8 + ko);
#pragma unroll
        for (int mt = 0; mt < 4; ++mt)
#pragma unroll
            for (int nt = 0; nt < 4; ++nt)
                acc[mt][nt] = __builtin_amdgcn_mfma_f32_16x16x32_bf16(a[mt], b[nt], acc[mt][nt], 0, 0, 0);
    }
#pragma unroll
    for (int mt = 0; mt < 4; ++mt)
#pragma unroll
        for (int nt = 0; nt < 4; ++nt) {
            int col = n0 + nt * 16 + r;
            if (col < VOC) {
#pragma unroll
                for (int rr = 0; rr < 4; ++rr) {
                    int row = m0 + mt * 16 + q * 4 + rr;
                    out[(size_t)row * VOC + col] = acc[mt][nt][rr];
                }
            }
        }
}

extern "C" void kernel_launch(void* const* d_in, const int* in_sizes, int n_in,
                              void* d_out, int out_size, void* d_ws, size_t ws_size,
                              hipStream_t stream) {
    const int*   idx     = (const int*)d_in[0];
    const float* wte     = (const float*)d_in[1];
    const float* ln1_g   = (const float*)d_in[2];
    const float* ln2_g   = (const float*)d_in[3];
    const float* w_up    = (const float*)d_in[4];
    const float* w_v     = (const float*)d_in[5];
    const float* w_cproj = (const float*)d_in[6];
    const float* w_scan  = (const float*)d_in[7];
    const float* identp  = (const float*)d_in[8];
    const float* w_fc    = (const float*)d_in[9];
    const float* w_proj  = (const float*)d_in[10];
    float* out = (float*)d_out;

    float* ws   = (float*)d_ws;
    float* x    = ws;
    float* buf0 = x    + (size_t)NPOS * C;
    float* buf1 = buf0 + (size_t)NPOS * C;
    float* vbuf = buf1 + (size_t)NPOS * C;
    float* hid  = vbuf + (size_t)NPOS * C;
    float* wuvT = hid  + (size_t)NPOS * HID;
    float* wcT  = wuvT + (size_t)NLAYER * C * 2 * C;
    float* wfcT = wcT  + (size_t)NLAYER * C * C;
    float* wpT  = wfcT + (size_t)NLAYER * C * HID;
    __hip_bfloat16* xbf   = (__hip_bfloat16*)(wpT + (size_t)NLAYER * HID * C);
    __hip_bfloat16* wtebf = xbf + (size_t)NPOS * KPAD;

    dim3 tg1((C * C + 255) / 256, NLAYER);
    transpose_k<<<tg1, 256, 0, stream>>>(w_up,    wuvT, C, C, 2 * C, 0, C * C, C * 2 * C);
    transpose_k<<<tg1, 256, 0, stream>>>(w_v,     wuvT, C, C, 2 * C, C, C * C, C * 2 * C);
    transpose_k<<<tg1, 256, 0, stream>>>(w_cproj, wcT,  C, C, C,     0, C * C, C * C);
    dim3 tg2((HID * C + 255) / 256, NLAYER);
    transpose_k<<<tg2, 256, 0, stream>>>(w_fc,   wfcT, HID, C, HID, 0, HID * C, C * HID);
    transpose_k<<<tg2, 256, 0, stream>>>(w_proj, wpT,  C, HID, C,   0, C * HID, HID * C);

    embed_k<<<NPOS * C / 256, 256, 0, stream>>>(idx, wte, x);

    for (int L = 0; L < NLAYER; ++L) {
        lnuv_k<<<NPOS / 8, 256, 0, stream>>>(x, ln1_g + L * C, wuvT + (size_t)L * C * 2 * C, buf0, vbuf);
        float* cur = buf0; float* oth = buf1;
        for (int off = 1; off < TT; off <<= 1) {
            scan_k<<<NPOS / 8, 256, 0, stream>>>(cur, oth, w_scan + (size_t)L * C * C, identp + L * C, off);
            float* tmp = cur; cur = oth; oth = tmp;
        }
        cproj_k<<<NPOS / 8, 256, 0, stream>>>(cur, vbuf, wcT + (size_t)L * C * C, x);
        lnfc_k<<<NPOS / 8, 256, 0, stream>>>(x, ln2_g + L * C, wfcT + (size_t)L * C * HID, hid);
        proj_k<<<NPOS / 8, 256, 0, stream>>>(hid, wpT + (size_t)L * HID * C, x);
    }

    convx_k<<<NPOS * KPAD / 256, 256, 0, stream>>>(x, xbf);
    convw_k<<<VOC, 256, 0, stream>>>(wte, wtebf);
    lmhead_k<<<dim3(16, 393), 256, 0, stream>>>((const __bf16*)xbf, (const __bf16*)wtebf, out);
}